// Round 5
// baseline (630.431 us; speedup 1.0000x reference)
//
#include <hip/hip_runtime.h>
#include <hip/hip_bf16.h>

#define T_SEQ 2048
#define NB 4
#define NE 2048
#define NH 16
#define NHKV 4
#define HD 128
#define KVD 512    // NHKV*HD
#define MTOT 8192  // NB*T_SEQ

typedef __attribute__((ext_vector_type(4))) float f32x4;
typedef __attribute__((ext_vector_type(16))) float f32x16;
typedef __attribute__((ext_vector_type(8))) __bf16 bf16x8;

__device__ __forceinline__ unsigned short f2bf(float f) {
  union { float f; unsigned int u; } x; x.f = f;
  unsigned int u = x.u;
  unsigned int r = (u + 0x7fffu + ((u >> 16) & 1u)) >> 16;
  return (unsigned short)r;
}

__device__ __forceinline__ unsigned cvtpk(float lo, float hi) {
  unsigned r;
  asm("v_cvt_pk_bf16_f32 %0, %1, %2" : "=v"(r) : "v"(lo), "v"(hi));
  return r;
}

__device__ __forceinline__ void plswap(unsigned &a, unsigned &b) {
  asm volatile("v_permlane32_swap_b32 %0, %1" : "+v"(a), "+v"(b));
}

typedef __attribute__((address_space(3))) unsigned int lds_uint;
typedef const __attribute__((address_space(1))) unsigned int glob_uint;

__device__ __forceinline__ void gload_lds16(const void* g, void* l) {
  __builtin_amdgcn_global_load_lds((glob_uint*)g, (lds_uint*)l, 16, 0, 0);
}

// ---------------- cast f32 -> bf16, 8 elems/thread ----------------
__global__ __launch_bounds__(256) void k_cast(const float* __restrict__ in,
                                              unsigned short* __restrict__ out, int n) {
  int i = (blockIdx.x * blockDim.x + threadIdx.x) * 8;
  if (i >= n) return;
  float4 a = *(const float4*)(in + i);
  float4 b = *(const float4*)(in + i + 4);
  union { unsigned short us[8]; uint4 v; } o;
  o.us[0] = f2bf(a.x); o.us[1] = f2bf(a.y); o.us[2] = f2bf(a.z); o.us[3] = f2bf(a.w);
  o.us[4] = f2bf(b.x); o.us[5] = f2bf(b.y); o.us[6] = f2bf(b.z); o.us[7] = f2bf(b.w);
  *(uint4*)(out + i) = o.v;
}

// ---------------- transpose + cast: in[K][N] f32 -> out[N][K] bf16 ----------------
__global__ __launch_bounds__(256) void k_transpose_cast(const float* __restrict__ in,
                                                        unsigned short* __restrict__ out,
                                                        int K, int N) {
  __shared__ float tile[32][33];
  int n0 = blockIdx.x * 32, k0 = blockIdx.y * 32;
  int tx = threadIdx.x & 31, ty = threadIdx.x >> 5;
#pragma unroll
  for (int r = 0; r < 4; ++r)
    tile[ty + r * 8][tx] = in[(k0 + ty + r * 8) * N + n0 + tx];
  __syncthreads();
#pragma unroll
  for (int r = 0; r < 4; ++r)
    out[(n0 + ty + r * 8) * K + k0 + tx] = f2bf(tile[tx][ty + r * 8]);
}

// ---------------- GEMM: C = A[M,K] @ Bt[N,K]^T (bf16 in, MFMA) ----------------
// STORE_MODE 2: f32 row-major into C0.
// STORE_MODE 3: fused QKV: n<2048 -> bf16 C0 (N=2048); n<2560 -> bf16 C1 (N=512);
//               else -> bf16 transposed into C2 = Vt[b][vd][t].
template <int STORE_MODE>
__global__ __launch_bounds__(256) void k_gemm(const unsigned short* __restrict__ A,
                                              const unsigned short* __restrict__ Bt,
                                              void* __restrict__ C0, void* __restrict__ C1,
                                              void* __restrict__ C2,
                                              int M, int N, int K) {
  __shared__ alignas(16) unsigned short lds[2][2][128 * 32];
  const int tid = threadIdx.x;
  const int w = tid >> 6, lane = tid & 63;
  const int lg = lane >> 4, ll = lane & 15;
  const int m0 = blockIdx.y * 128, n0 = blockIdx.x * 128;
  const int wr = (w >> 1) * 64, wc = (w & 1) * 64;

  f32x4 acc[4][4] = {};
  const int NT = K >> 5;
  int cur = 0;

  auto STAGE = [&](int buf, int t) {
    int k0 = t << 5;
#pragma unroll
    for (int is = 0; is < 2; ++is) {
      int chunk = is * 256 + tid;
      int r = chunk >> 2, c = chunk & 3;
      int sc = (c ^ ((r >> 1) & 3)) << 3;
      gload_lds16(A + (m0 + r) * K + k0 + sc, &lds[buf][0][(is * 256 + (w << 6)) * 8]);
      gload_lds16(Bt + (n0 + r) * K + k0 + sc, &lds[buf][1][(is * 256 + (w << 6)) * 8]);
    }
  };

  auto COMPUTE = [&](int buf) {
    const unsigned short* La = lds[buf][0];
    const unsigned short* Lb = lds[buf][1];
    bf16x8 af[4], bfr[4];
#pragma unroll
    for (int mf = 0; mf < 4; ++mf) {
      int r = wr + mf * 16 + ll;
      int c = lg ^ ((r >> 1) & 3);
      af[mf] = *(const bf16x8*)(La + r * 32 + c * 8);
    }
#pragma unroll
    for (int nf = 0; nf < 4; ++nf) {
      int r = wc + nf * 16 + ll;
      int c = lg ^ ((r >> 1) & 3);
      bfr[nf] = *(const bf16x8*)(Lb + r * 32 + c * 8);
    }
#pragma unroll
    for (int mf = 0; mf < 4; ++mf)
#pragma unroll
      for (int nf = 0; nf < 4; ++nf)
        acc[mf][nf] = __builtin_amdgcn_mfma_f32_16x16x32_bf16(af[mf], bfr[nf], acc[mf][nf], 0, 0, 0);
  };

  STAGE(0, 0);
  __syncthreads();
  for (int t = 0; t < NT - 1; ++t) {
    STAGE(cur ^ 1, t + 1);
    COMPUTE(cur);
    __syncthreads();
    cur ^= 1;
  }
  COMPUTE(cur);

  if (STORE_MODE == 2) {
    float* Cp = (float*)C0;
#pragma unroll
    for (int mf = 0; mf < 4; ++mf)
#pragma unroll
      for (int nf = 0; nf < 4; ++nf) {
        int row = m0 + wr + mf * 16 + (lg << 2);
        int col = n0 + wc + nf * 16 + ll;
#pragma unroll
        for (int i = 0; i < 4; ++i)
          Cp[(size_t)(row + i) * N + col] = acc[mf][nf][i];
      }
  } else {  // STORE_MODE == 3
    if (n0 < 2048) {
      unsigned short* Cp = (unsigned short*)C0;
#pragma unroll
      for (int mf = 0; mf < 4; ++mf)
#pragma unroll
        for (int nf = 0; nf < 4; ++nf) {
          int row = m0 + wr + mf * 16 + (lg << 2);
          int col = n0 + wc + nf * 16 + ll;
#pragma unroll
          for (int i = 0; i < 4; ++i)
            Cp[(size_t)(row + i) * 2048 + col] = f2bf(acc[mf][nf][i]);
        }
    } else if (n0 < 2560) {
      unsigned short* Cp = (unsigned short*)C1;
#pragma unroll
      for (int mf = 0; mf < 4; ++mf)
#pragma unroll
        for (int nf = 0; nf < 4; ++nf) {
          int row = m0 + wr + mf * 16 + (lg << 2);
          int col = n0 + wc + nf * 16 + ll - 2048;
#pragma unroll
          for (int i = 0; i < 4; ++i)
            Cp[(size_t)(row + i) * 512 + col] = f2bf(acc[mf][nf][i]);
        }
    } else {
      unsigned short* Cp = (unsigned short*)C2;
#pragma unroll
      for (int mf = 0; mf < 4; ++mf)
#pragma unroll
        for (int nf = 0; nf < 4; ++nf) {
          int m = m0 + wr + mf * 16 + (lg << 2);
          int vd = n0 + wc + nf * 16 + ll - 2560;
          int base = (m >> 11) * (KVD * T_SEQ) + vd * T_SEQ + (m & 2047);
          union { unsigned short us[4]; uint2 v; } pk;
#pragma unroll
          for (int i = 0; i < 4; ++i) pk.us[i] = f2bf(acc[mf][nf][i]);
          *(uint2*)(Cp + base) = pk.v;
        }
    }
  }
}

// ---------------- Flash attention, ALiBi + causal, GQA — 8-wave, swapped 32x32 ----------------
// Waves 0-3: qt = p; waves 4-7: qt = 15-p (concurrent, shared K/V staging).
// p flipped by (bb>>1)&1 so co-resident blocks carry balanced work.
__global__ __launch_bounds__(512, 4) void k_attn8(const unsigned short* __restrict__ Q,
                                                  const unsigned short* __restrict__ Kp,
                                                  const unsigned short* __restrict__ Vt,
                                                  unsigned short* __restrict__ Y) {
  __shared__ alignas(16) unsigned short Klds[2][64 * 128];  // [k][d], 16B chunk c ^= (k&15)
  __shared__ alignas(16) unsigned short Vlds[2][128 * 64];  // [d][k], 16B chunk c ^= (d&7)

  const int tid = threadIdx.x, w = tid >> 6, lane = tid & 63;
  const int l31 = lane & 31, hi = lane >> 5;
  const int h = blockIdx.y, bb = blockIdx.z;
  const int hkv = h >> 2;
  const float L2E = 1.4426950408889634f;
  const float slopeL2 = exp2f(-0.5f * (float)(hkv + 1)) * L2E;
  const float c0 = 0.08838834764831845f * L2E;  // (1/sqrt(128))*log2e

  const unsigned short* Kbase = Kp + (size_t)bb * T_SEQ * KVD + hkv * HD;
  const unsigned short* Vbase = Vt + ((size_t)bb * KVD + hkv * HD) * T_SEQ;

  const int p = ((bb >> 1) & 1) ? 7 - (int)blockIdx.x : (int)blockIdx.x;
  const int qt = (w < 4) ? p : 15 - p;
  const int q0 = qt * 128;
  const int qbase = q0 + (w & 3) * 32;
  const int qrow = bb * T_SEQ + qbase + l31;

  bf16x8 qf[8];
#pragma unroll
  for (int ds = 0; ds < 8; ++ds)
    qf[ds] = *(const bf16x8*)(Q + (size_t)qrow * NE + h * HD + ds * 16 + hi * 8);

  f32x16 yacc[4] = {};
  float mrun = -1e30f, lrun = 0.f;
  const float qbias = slopeL2 * (float)(qbase + l31);

  auto STAGE = [&](int buf, int kt) {
    int kt0 = kt * 64;
#pragma unroll
    for (int is = 0; is < 2; ++is) {  // K: 64 rows x 16 chunks = 1024
      int chunk = is * 512 + tid;
      int r = chunk >> 4, c = chunk & 15;
      gload_lds16(Kbase + (size_t)(kt0 + r) * KVD + ((c ^ (r & 15)) << 3),
                  &Klds[buf][(is * 512 + w * 64) * 8]);
    }
#pragma unroll
    for (int is = 0; is < 2; ++is) {  // V: 128 rows x 8 chunks = 1024
      int chunk = is * 512 + tid;
      int r = chunk >> 3, c = chunk & 7;
      gload_lds16(Vbase + (size_t)r * T_SEQ + kt0 + ((c ^ (r & 7)) << 3),
                  &Vlds[buf][(is * 512 + w * 64) * 8]);
    }
  };

  const int nkt_hi = 2 * (16 - p);  // union range (covers qt_hi = 15-p)
  int cur = 0;
  STAGE(0, 0);
  for (int kt = 0; kt < nkt_hi; ++kt) {
    if (kt + 1 < nkt_hi) {
      STAGE(cur ^ 1, kt + 1);
      asm volatile("s_waitcnt vmcnt(4)" ::: "memory");  // 4/thread just issued stay in flight
    } else {
      asm volatile("s_waitcnt vmcnt(0)" ::: "memory");
    }
    __builtin_amdgcn_s_barrier();
    __builtin_amdgcn_sched_barrier(0);

    const unsigned short* Kl = Klds[cur];
    const unsigned short* Vl = Vlds[cur];
    const int kt0 = kt * 64;
    const bool alive = (kt0 < qbase + 32);  // wave-uniform

    if (alive) {
      // ---- S^T[k][q] = K_tile @ Q^T ----
      f32x16 sacc[2] = {};
      __builtin_amdgcn_s_setprio(1);
#pragma unroll
      for (int ds = 0; ds < 8; ++ds) {
#pragma unroll
        for (int kf = 0; kf < 2; ++kf) {
          int row = kf * 32 + l31;
          int c = (2 * ds + hi) ^ (row & 15);
          bf16x8 kfv = *(const bf16x8*)(Kl + row * 128 + c * 8);
          sacc[kf] = __builtin_amdgcn_mfma_f32_32x32x16_bf16(kfv, qf[ds], sacc[kf], 0, 0, 0);
        }
      }
      __builtin_amdgcn_s_setprio(0);

      // ---- bias + causal mask + in-register online softmax ----
      const bool masked = (kt0 + 63 > qbase);  // wave-uniform
      const float base0 = slopeL2 * (float)(kt0 + 4 * hi) - qbias;
      const int lim = qbase + l31 - kt0 - 4 * hi;
      float mx = -1e30f;
#pragma unroll
      for (int kf = 0; kf < 2; ++kf)
#pragma unroll
        for (int r = 0; r < 16; ++r) {
          const int ckoff = kf * 32 + (r & 3) + 8 * (r >> 2);
          float a = fmaf(sacc[kf][r], c0, fmaf((float)ckoff, slopeL2, base0));
          if (masked) a = (ckoff <= lim) ? a : -1e30f;
          sacc[kf][r] = a;
          mx = fmaxf(mx, a);
        }
      mx = fmaxf(mx, __shfl_xor(mx, 32, 64));
      if (!__all(mx <= mrun + 8.f)) {  // T13 defer-max
        const float mnew = fmaxf(mrun, mx);
        const float alpha = exp2f(mrun - mnew);
        mrun = mnew;
        lrun *= alpha;
#pragma unroll
        for (int df = 0; df < 4; ++df)
#pragma unroll
          for (int r = 0; r < 16; ++r) yacc[df][r] *= alpha;
      }
      float sm = 0.f;
#pragma unroll
      for (int kf = 0; kf < 2; ++kf)
#pragma unroll
        for (int r = 0; r < 16; ++r) {
          float pv = exp2f(sacc[kf][r] - mrun);
          sacc[kf][r] = pv;
          sm += pv;
        }
      sm += __shfl_xor(sm, 32, 64);
      lrun += sm;

      // ---- P -> bf16 B-fragments (cvt_pk + permlane32_swap) ----
      unsigned cpk[2][8];
#pragma unroll
      for (int kf = 0; kf < 2; ++kf)
#pragma unroll
        for (int j = 0; j < 8; ++j)
          cpk[kf][j] = cvtpk(sacc[kf][2 * j], sacc[kf][2 * j + 1]);

      bf16x8 pb[4];
#pragma unroll
      for (int ks = 0; ks < 4; ++ks) {
        unsigned a0 = cpk[ks >> 1][4 * (ks & 1) + 0];
        unsigned b0 = cpk[ks >> 1][4 * (ks & 1) + 2];
        unsigned a1 = cpk[ks >> 1][4 * (ks & 1) + 1];
        unsigned b1 = cpk[ks >> 1][4 * (ks & 1) + 3];
        plswap(a0, b0);
        plswap(a1, b1);
        union { unsigned u[4]; bf16x8 v; } pk;
        pk.u[0] = a0; pk.u[1] = a1; pk.u[2] = b0; pk.u[3] = b1;
        pb[ks] = pk.v;
      }

      // ---- y^T += V^T @ P^T ----
      __builtin_amdgcn_s_setprio(1);
#pragma unroll
      for (int df = 0; df < 4; ++df) {
#pragma unroll
        for (int ks = 0; ks < 4; ++ks) {
          int row = 32 * df + l31;
          int c = (2 * ks + hi) ^ (row & 7);
          bf16x8 vf = *(const bf16x8*)(Vl + row * 64 + c * 8);
          yacc[df] = __builtin_amdgcn_mfma_f32_32x32x16_bf16(vf, pb[ks], yacc[df], 0, 0, 0);
        }
      }
      __builtin_amdgcn_s_setprio(0);
    }

    __builtin_amdgcn_sched_barrier(0);
    __builtin_amdgcn_s_barrier();
    cur ^= 1;
  }

  // ---- epilogue: normalize + store bf16 ----
  const float inv = 1.f / lrun;
#pragma unroll
  for (int df = 0; df < 4; ++df)
#pragma unroll
    for (int g = 0; g < 4; ++g) {
      unsigned u0 = cvtpk(yacc[df][4 * g + 0] * inv, yacc[df][4 * g + 1] * inv);
      unsigned u1 = cvtpk(yacc[df][4 * g + 2] * inv, yacc[df][4 * g + 3] * inv);
      union { unsigned u[2]; uint2 v; } pk;
      pk.u[0] = u0; pk.u[1] = u1;
      *(uint2*)(Y + (size_t)qrow * NE + h * HD + 32 * df + 8 * g + 4 * hi) = pk.v;
    }
}

extern "C" void kernel_launch(void* const* d_in, const int* in_sizes, int n_in,
                              void* d_out, int out_size, void* d_ws, size_t ws_size,
                              hipStream_t stream) {
  const float* x = (const float*)d_in[0];
  const float* Wq = (const float*)d_in[1];
  const float* Wk = (const float*)d_in[2];
  const float* Wv = (const float*)d_in[3];
  const float* Wo = (const float*)d_in[4];

  unsigned short* ws = (unsigned short*)d_ws;
  unsigned short* xb    = ws;              // x bf16 [8192][2048]; reused as Y
  unsigned short* Wqkvt = ws + 16777216;   // [3072][2048] (Wq^T | Wk^T | Wv^T)
  unsigned short* Wot   = ws + 23068672;   // [2048][2048]
  unsigned short* Qb    = ws + 27262976;   // [8192][2048]
  unsigned short* Kb    = ws + 44040192;   // [8192][512]
  unsigned short* Vtb   = ws + 48234496;   // [4][512][2048]
  unsigned short* Yb    = xb;

  k_cast<<<8192, 256, 0, stream>>>(x, xb, 16777216);
  k_transpose_cast<<<dim3(64, 64), 256, 0, stream>>>(Wq, Wqkvt, 2048, 2048);
  k_transpose_cast<<<dim3(16, 64), 256, 0, stream>>>(Wk, Wqkvt + 2048 * 2048, 2048, 512);
  k_transpose_cast<<<dim3(16, 64), 256, 0, stream>>>(Wv, Wqkvt + 2560 * 2048, 2048, 512);
  k_transpose_cast<<<dim3(64, 64), 256, 0, stream>>>(Wo, Wot, 2048, 2048);

  k_gemm<3><<<dim3(24, 64), 256, 0, stream>>>(xb, Wqkvt, Qb, Kb, Vtb, MTOT, 3072, 2048);

  k_attn8<<<dim3(8, 16, 4), 512, 0, stream>>>(Qb, Kb, Vtb, Yb);

  k_gemm<2><<<dim3(16, 64), 256, 0, stream>>>(Yb, Wot, d_out, nullptr, nullptr, MTOT, 2048, 2048);
}

// Round 6
// 621.044 us; speedup vs baseline: 1.0151x; 1.0151x over previous
//
#include <hip/hip_runtime.h>
#include <hip/hip_bf16.h>

#define T_SEQ 2048
#define NB 4
#define NE 2048
#define NH 16
#define NHKV 4
#define HD 128
#define KVD 512    // NHKV*HD
#define MTOT 8192  // NB*T_SEQ

typedef __attribute__((ext_vector_type(4))) float f32x4;
typedef __attribute__((ext_vector_type(16))) float f32x16;
typedef __attribute__((ext_vector_type(8))) __bf16 bf16x8;

__device__ __forceinline__ unsigned short f2bf(float f) {
  union { float f; unsigned int u; } x; x.f = f;
  unsigned int u = x.u;
  unsigned int r = (u + 0x7fffu + ((u >> 16) & 1u)) >> 16;
  return (unsigned short)r;
}

__device__ __forceinline__ unsigned cvtpk(float lo, float hi) {
  unsigned r;
  asm("v_cvt_pk_bf16_f32 %0, %1, %2" : "=v"(r) : "v"(lo), "v"(hi));
  return r;
}

__device__ __forceinline__ void plswap(unsigned &a, unsigned &b) {
  asm volatile("v_permlane32_swap_b32 %0, %1" : "+v"(a), "+v"(b));
}

typedef __attribute__((address_space(3))) unsigned int lds_uint;
typedef const __attribute__((address_space(1))) unsigned int glob_uint;

__device__ __forceinline__ void gload_lds16(const void* g, void* l) {
  __builtin_amdgcn_global_load_lds((glob_uint*)g, (lds_uint*)l, 16, 0, 0);
}

// ---------------- cast f32 -> bf16, 8 elems/thread ----------------
__global__ __launch_bounds__(256) void k_cast(const float* __restrict__ in,
                                              unsigned short* __restrict__ out, int n) {
  int i = (blockIdx.x * blockDim.x + threadIdx.x) * 8;
  if (i >= n) return;
  float4 a = *(const float4*)(in + i);
  float4 b = *(const float4*)(in + i + 4);
  union { unsigned short us[8]; uint4 v; } o;
  o.us[0] = f2bf(a.x); o.us[1] = f2bf(a.y); o.us[2] = f2bf(a.z); o.us[3] = f2bf(a.w);
  o.us[4] = f2bf(b.x); o.us[5] = f2bf(b.y); o.us[6] = f2bf(b.z); o.us[7] = f2bf(b.w);
  *(uint4*)(out + i) = o.v;
}

// ---------------- transpose + cast: in[K][N] f32 -> out[N][K] bf16 ----------------
__global__ __launch_bounds__(256) void k_transpose_cast(const float* __restrict__ in,
                                                        unsigned short* __restrict__ out,
                                                        int K, int N) {
  __shared__ float tile[32][33];
  int n0 = blockIdx.x * 32, k0 = blockIdx.y * 32;
  int tx = threadIdx.x & 31, ty = threadIdx.x >> 5;
#pragma unroll
  for (int r = 0; r < 4; ++r)
    tile[ty + r * 8][tx] = in[(k0 + ty + r * 8) * N + n0 + tx];
  __syncthreads();
#pragma unroll
  for (int r = 0; r < 4; ++r)
    out[(n0 + ty + r * 8) * K + k0 + tx] = f2bf(tile[tx][ty + r * 8]);
}

// ---------------- GEMM: C = A[M,K] @ Bt[N,K]^T (bf16 in, MFMA) ----------------
// STORE_MODE 2: f32 row-major into C0.
// STORE_MODE 3: fused QKV: n<2048 -> bf16 C0 (N=2048); n<2560 -> bf16 C1 (N=512);
//               else -> bf16 transposed into C2 = Vt[b][vd][t].
template <int STORE_MODE>
__global__ __launch_bounds__(256) void k_gemm(const unsigned short* __restrict__ A,
                                              const unsigned short* __restrict__ Bt,
                                              void* __restrict__ C0, void* __restrict__ C1,
                                              void* __restrict__ C2,
                                              int M, int N, int K) {
  __shared__ alignas(16) unsigned short lds[2][2][128 * 32];
  const int tid = threadIdx.x;
  const int w = tid >> 6, lane = tid & 63;
  const int lg = lane >> 4, ll = lane & 15;
  const int m0 = blockIdx.y * 128, n0 = blockIdx.x * 128;
  const int wr = (w >> 1) * 64, wc = (w & 1) * 64;

  f32x4 acc[4][4] = {};
  const int NT = K >> 5;
  int cur = 0;

  auto STAGE = [&](int buf, int t) {
    int k0 = t << 5;
#pragma unroll
    for (int is = 0; is < 2; ++is) {
      int chunk = is * 256 + tid;
      int r = chunk >> 2, c = chunk & 3;
      int sc = (c ^ ((r >> 1) & 3)) << 3;
      gload_lds16(A + (m0 + r) * K + k0 + sc, &lds[buf][0][(is * 256 + (w << 6)) * 8]);
      gload_lds16(Bt + (n0 + r) * K + k0 + sc, &lds[buf][1][(is * 256 + (w << 6)) * 8]);
    }
  };

  auto COMPUTE = [&](int buf) {
    const unsigned short* La = lds[buf][0];
    const unsigned short* Lb = lds[buf][1];
    bf16x8 af[4], bfr[4];
#pragma unroll
    for (int mf = 0; mf < 4; ++mf) {
      int r = wr + mf * 16 + ll;
      int c = lg ^ ((r >> 1) & 3);
      af[mf] = *(const bf16x8*)(La + r * 32 + c * 8);
    }
#pragma unroll
    for (int nf = 0; nf < 4; ++nf) {
      int r = wc + nf * 16 + ll;
      int c = lg ^ ((r >> 1) & 3);
      bfr[nf] = *(const bf16x8*)(Lb + r * 32 + c * 8);
    }
#pragma unroll
    for (int mf = 0; mf < 4; ++mf)
#pragma unroll
      for (int nf = 0; nf < 4; ++nf)
        acc[mf][nf] = __builtin_amdgcn_mfma_f32_16x16x32_bf16(af[mf], bfr[nf], acc[mf][nf], 0, 0, 0);
  };

  STAGE(0, 0);
  __syncthreads();
  for (int t = 0; t < NT - 1; ++t) {
    STAGE(cur ^ 1, t + 1);
    COMPUTE(cur);
    __syncthreads();
    cur ^= 1;
  }
  COMPUTE(cur);

  if (STORE_MODE == 2) {
    float* Cp = (float*)C0;
#pragma unroll
    for (int mf = 0; mf < 4; ++mf)
#pragma unroll
      for (int nf = 0; nf < 4; ++nf) {
        int row = m0 + wr + mf * 16 + (lg << 2);
        int col = n0 + wc + nf * 16 + ll;
#pragma unroll
        for (int i = 0; i < 4; ++i)
          Cp[(size_t)(row + i) * N + col] = acc[mf][nf][i];
      }
  } else {  // STORE_MODE == 3
    if (n0 < 2048) {
      unsigned short* Cp = (unsigned short*)C0;
#pragma unroll
      for (int mf = 0; mf < 4; ++mf)
#pragma unroll
        for (int nf = 0; nf < 4; ++nf) {
          int row = m0 + wr + mf * 16 + (lg << 2);
          int col = n0 + wc + nf * 16 + ll;
#pragma unroll
          for (int i = 0; i < 4; ++i)
            Cp[(size_t)(row + i) * 2048 + col] = f2bf(acc[mf][nf][i]);
        }
    } else if (n0 < 2560) {
      unsigned short* Cp = (unsigned short*)C1;
#pragma unroll
      for (int mf = 0; mf < 4; ++mf)
#pragma unroll
        for (int nf = 0; nf < 4; ++nf) {
          int row = m0 + wr + mf * 16 + (lg << 2);
          int col = n0 + wc + nf * 16 + ll - 2048;
#pragma unroll
          for (int i = 0; i < 4; ++i)
            Cp[(size_t)(row + i) * 512 + col] = f2bf(acc[mf][nf][i]);
        }
    } else {
      unsigned short* Cp = (unsigned short*)C2;
#pragma unroll
      for (int mf = 0; mf < 4; ++mf)
#pragma unroll
        for (int nf = 0; nf < 4; ++nf) {
          int m = m0 + wr + mf * 16 + (lg << 2);
          int vd = n0 + wc + nf * 16 + ll - 2560;
          int base = (m >> 11) * (KVD * T_SEQ) + vd * T_SEQ + (m & 2047);
          union { unsigned short us[4]; uint2 v; } pk;
#pragma unroll
          for (int i = 0; i < 4; ++i) pk.us[i] = f2bf(acc[mf][nf][i]);
          *(uint2*)(Cp + base) = pk.v;
        }
    }
  }
}

// ---------------- Flash attention, ALiBi + causal, GQA — 4-wave, KVBLK=32, swapped 32x32 ----------------
// One 128-row q-tile per block (wave w: rows qbase..qbase+31). Grid 16x16x4 = 1024 blocks.
// t scrambled (LPT + z-stagger) so co-resident blocks have mixed sizes.
// No VGPR cap (R5 lesson: launch_bounds cap below footprint -> spill catastrophe).
__global__ __launch_bounds__(256) void k_attn4(const unsigned short* __restrict__ Q,
                                               const unsigned short* __restrict__ Kp,
                                               const unsigned short* __restrict__ Vt,
                                               unsigned short* __restrict__ Y) {
  __shared__ alignas(16) unsigned short Klds[2][32 * 128];  // [k][d], 16B chunk c ^= (k&15)
  __shared__ alignas(16) unsigned short Vlds[2][128 * 32];  // [d][k], 16B chunk c ^= (d&3)

  const int tid = threadIdx.x, w = tid >> 6, lane = tid & 63;
  const int l31 = lane & 31, hi = lane >> 5;
  const int h = blockIdx.y, bb = blockIdx.z;
  const int hkv = h >> 2;
  const float L2E = 1.4426950408889634f;
  const float slopeL2 = exp2f(-0.5f * (float)(hkv + 1)) * L2E;
  const float c0 = 0.08838834764831845f * L2E;  // (1/sqrt(128))*log2e

  const unsigned short* Kbase = Kp + (size_t)bb * T_SEQ * KVD + hkv * HD;
  const unsigned short* Vbase = Vt + ((size_t)bb * KVD + hkv * HD) * T_SEQ;

  const int t = ((15 - (int)blockIdx.x) + 4 * (int)blockIdx.z) & 15;
  const int q0 = t * 128;
  const int qbase = q0 + w * 32;
  const int qrow = bb * T_SEQ + qbase + l31;

  // Q^T B-fragments: lane holds Q[q=l31-row][k-slices], 16B contiguous per slice
  bf16x8 qf[8];
#pragma unroll
  for (int ds = 0; ds < 8; ++ds)
    qf[ds] = *(const bf16x8*)(Q + (size_t)qrow * NE + h * HD + ds * 16 + hi * 8);

  f32x16 yacc[4] = {};
  float mrun = -1e30f, lrun = 0.f;
  const float qbias = slopeL2 * (float)(qbase + l31);

  auto STAGE = [&](int buf, int kt) {
    int kt0 = kt * 32;
#pragma unroll
    for (int is = 0; is < 2; ++is) {  // K: 32 rows x 16 chunks = 512
      int chunk = is * 256 + tid;
      int r = chunk >> 4, c = chunk & 15;
      gload_lds16(Kbase + (size_t)(kt0 + r) * KVD + ((c ^ (r & 15)) << 3),
                  &Klds[buf][(is * 256 + w * 64) * 8]);
    }
#pragma unroll
    for (int is = 0; is < 2; ++is) {  // V: 128 rows x 4 chunks = 512
      int chunk = is * 256 + tid;
      int r = chunk >> 2, c = chunk & 3;
      gload_lds16(Vbase + (size_t)r * T_SEQ + kt0 + ((c ^ (r & 3)) << 3),
                  &Vlds[buf][(is * 256 + w * 64) * 8]);
    }
  };

  const int nkt = 4 * (t + 1);
  int cur = 0;
  STAGE(0, 0);
  for (int kt = 0; kt < nkt; ++kt) {
    if (kt + 1 < nkt) {
      STAGE(cur ^ 1, kt + 1);
      asm volatile("s_waitcnt vmcnt(4)" ::: "memory");  // 4 just-issued stay in flight
    } else {
      asm volatile("s_waitcnt vmcnt(0)" ::: "memory");
    }
    __builtin_amdgcn_s_barrier();
    __builtin_amdgcn_sched_barrier(0);

    const unsigned short* Kl = Klds[cur];
    const unsigned short* Vl = Vlds[cur];
    const int kt0 = kt * 32;
    const bool alive = (kt0 < qbase + 32);  // wave-uniform

    if (alive) {
      // ---- S^T[k][q] = K_tile @ Q^T ----
      f32x16 sacc = {};
      __builtin_amdgcn_s_setprio(1);
#pragma unroll
      for (int ds = 0; ds < 8; ++ds) {
        int c = (2 * ds + hi) ^ (l31 & 15);
        bf16x8 kfv = *(const bf16x8*)(Kl + l31 * 128 + c * 8);
        sacc = __builtin_amdgcn_mfma_f32_32x32x16_bf16(kfv, qf[ds], sacc, 0, 0, 0);
      }
      __builtin_amdgcn_s_setprio(0);

      // ---- bias + causal mask + in-register online softmax ----
      const bool masked = (kt0 + 31 > qbase);  // wave-uniform
      const float base0 = slopeL2 * (float)(kt0 + 4 * hi) - qbias;
      const int lim = qbase + l31 - kt0 - 4 * hi;
      float mx = -1e30f;
#pragma unroll
      for (int r = 0; r < 16; ++r) {
        const int ck = (r & 3) + 8 * (r >> 2);
        float a = fmaf(sacc[r], c0, fmaf((float)ck, slopeL2, base0));
        if (masked) a = (ck <= lim) ? a : -1e30f;
        sacc[r] = a;
        mx = fmaxf(mx, a);
      }
      mx = fmaxf(mx, __shfl_xor(mx, 32, 64));
      if (!__all(mx <= mrun + 8.f)) {  // T13 defer-max
        const float mnew = fmaxf(mrun, mx);
        const float alpha = exp2f(mrun - mnew);
        mrun = mnew;
        lrun *= alpha;
#pragma unroll
        for (int df = 0; df < 4; ++df)
#pragma unroll
          for (int r = 0; r < 16; ++r) yacc[df][r] *= alpha;
      }
      float sm = 0.f;
#pragma unroll
      for (int r = 0; r < 16; ++r) {
        float pv = exp2f(sacc[r] - mrun);
        sacc[r] = pv;
        sm += pv;
      }
      sm += __shfl_xor(sm, 32, 64);
      lrun += sm;

      // ---- P -> bf16 B-fragments (cvt_pk + permlane32_swap) ----
      unsigned cpk[8];
#pragma unroll
      for (int j = 0; j < 8; ++j)
        cpk[j] = cvtpk(sacc[2 * j], sacc[2 * j + 1]);

      bf16x8 pb[2];
#pragma unroll
      for (int j = 0; j < 2; ++j) {
        unsigned a0 = cpk[4 * j + 0];
        unsigned b0 = cpk[4 * j + 2];
        unsigned a1 = cpk[4 * j + 1];
        unsigned b1 = cpk[4 * j + 3];
        plswap(a0, b0);
        plswap(a1, b1);
        union { unsigned u[4]; bf16x8 v; } pk;
        pk.u[0] = a0; pk.u[1] = a1; pk.u[2] = b0; pk.u[3] = b1;
        pb[j] = pk.v;
      }

      // ---- y^T += V^T @ P^T ----
      __builtin_amdgcn_s_setprio(1);
#pragma unroll
      for (int df = 0; df < 4; ++df) {
        int row = 32 * df + l31;
#pragma unroll
        for (int j = 0; j < 2; ++j) {
          int c = (2 * j + hi) ^ (row & 3);
          bf16x8 vf = *(const bf16x8*)(Vl + row * 32 + c * 8);
          yacc[df] = __builtin_amdgcn_mfma_f32_32x32x16_bf16(vf, pb[j], yacc[df], 0, 0, 0);
        }
      }
      __builtin_amdgcn_s_setprio(0);
    }

    __builtin_amdgcn_sched_barrier(0);
    __builtin_amdgcn_s_barrier();
    cur ^= 1;
  }

  // ---- epilogue: normalize + store bf16 ----
  const float inv = 1.f / lrun;
#pragma unroll
  for (int df = 0; df < 4; ++df)
#pragma unroll
    for (int g = 0; g < 4; ++g) {
      unsigned u0 = cvtpk(yacc[df][4 * g + 0] * inv, yacc[df][4 * g + 1] * inv);
      unsigned u1 = cvtpk(yacc[df][4 * g + 2] * inv, yacc[df][4 * g + 3] * inv);
      union { unsigned u[2]; uint2 v; } pk;
      pk.u[0] = u0; pk.u[1] = u1;
      *(uint2*)(Y + (size_t)qrow * NE + h * HD + 32 * df + 8 * g + 4 * hi) = pk.v;
    }
}

extern "C" void kernel_launch(void* const* d_in, const int* in_sizes, int n_in,
                              void* d_out, int out_size, void* d_ws, size_t ws_size,
                              hipStream_t stream) {
  const float* x = (const float*)d_in[0];
  const float* Wq = (const float*)d_in[1];
  const float* Wk = (const float*)d_in[2];
  const float* Wv = (const float*)d_in[3];
  const float* Wo = (const float*)d_in[4];

  unsigned short* ws = (unsigned short*)d_ws;
  unsigned short* xb    = ws;              // x bf16 [8192][2048]; reused as Y
  unsigned short* Wqkvt = ws + 16777216;   // [3072][2048] (Wq^T | Wk^T | Wv^T)
  unsigned short* Wot   = ws + 23068672;   // [2048][2048]
  unsigned short* Qb    = ws + 27262976;   // [8192][2048]
  unsigned short* Kb    = ws + 44040192;   // [8192][512]
  unsigned short* Vtb   = ws + 48234496;   // [4][512][2048]
  unsigned short* Yb    = xb;

  k_cast<<<8192, 256, 0, stream>>>(x, xb, 16777216);
  k_transpose_cast<<<dim3(64, 64), 256, 0, stream>>>(Wq, Wqkvt, 2048, 2048);
  k_transpose_cast<<<dim3(16, 64), 256, 0, stream>>>(Wk, Wqkvt + 2048 * 2048, 2048, 512);
  k_transpose_cast<<<dim3(16, 64), 256, 0, stream>>>(Wv, Wqkvt + 2560 * 2048, 2048, 512);
  k_transpose_cast<<<dim3(64, 64), 256, 0, stream>>>(Wo, Wot, 2048, 2048);

  k_gemm<3><<<dim3(24, 64), 256, 0, stream>>>(xb, Wqkvt, Qb, Kb, Vtb, MTOT, 3072, 2048);

  k_attn4<<<dim3(16, 16, 4), 256, 0, stream>>>(Qb, Kb, Vtb, Yb);

  k_gemm<2><<<dim3(16, 64), 256, 0, stream>>>(Yb, Wot, d_out, nullptr, nullptr, MTOT, 2048, 2048);
}